// Round 9
// baseline (363.284 us; speedup 1.0000x reference)
//
#include <hip/hip_runtime.h>
#include <hip/hip_bf16.h>
#include <hip/hip_fp16.h>

#define NN 100000     // nodes
#define FIN 128
#define EMB 64
#define SCAN_B 256

using half8 = __attribute__((ext_vector_type(8))) _Float16;
using f32x4 = __attribute__((ext_vector_type(4))) float;

// ---------------------------------------------------------------- degree ----
// Device-scope atomics execute past the (non-coherent) per-XCD L2s at the
// shared memory side, so no dst-partitioning: each edge read exactly once.
__global__ void cnt_count_k(const int* __restrict__ dst, int* __restrict__ cnt, int n_edges) {
    int e = blockIdx.x * blockDim.x + threadIdx.x;
    if (e < n_edges) atomicAdd(&cnt[dst[e]], 1);
}

// ---------------------------------------------------------------- scan ------
__global__ void scan1_k(const int* __restrict__ cnt, int* __restrict__ excl,
                        int* __restrict__ bsum, float* __restrict__ dinv, int n) {
    __shared__ int tmp[SCAN_B];
    int tid = threadIdx.x;
    int i = blockIdx.x * SCAN_B + tid;
    int v = (i < n) ? cnt[i] : 0;
    if (i < n) dinv[i] = rsqrtf((float)(v + 1));   // +1 self-loop
    tmp[tid] = v; __syncthreads();
    for (int off = 1; off < SCAN_B; off <<= 1) {
        int t = (tid >= off) ? tmp[tid - off] : 0; __syncthreads();
        tmp[tid] += t; __syncthreads();
    }
    if (i < n) excl[i] = tmp[tid] - v;
    if (tid == SCAN_B - 1) bsum[blockIdx.x] = tmp[tid];
}

__global__ void scan2_k(int* __restrict__ bsum, int nb) {   // single block, nb<=512
    __shared__ int tmp[512];
    int tid = threadIdx.x;
    int v = (tid < nb) ? bsum[tid] : 0;
    tmp[tid] = v; __syncthreads();
    for (int off = 1; off < 512; off <<= 1) {
        int t = (tid >= off) ? tmp[tid - off] : 0; __syncthreads();
        tmp[tid] += t; __syncthreads();
    }
    if (tid < nb) bsum[tid] = tmp[tid] - v;
}

__global__ void scan3_k(const int* __restrict__ excl, const int* __restrict__ bsum,
                        int* __restrict__ rowptr, int* __restrict__ fill, int n, int n_edges) {
    int i = blockIdx.x * SCAN_B + threadIdx.x;
    if (i < n) {
        int r = excl[i] + bsum[blockIdx.x];
        rowptr[i] = r;
        fill[i] = r;
    }
    if (i == 0) rowptr[n] = n_edges;
}

// ---------------------------------------------------------------- fill ------
// Scattered csr store is NON-TEMPORAL: no L2 allocate, write-through toward
// the shared memory-side cache where 4B writes from all XCDs coalesce into
// full lines (kills the partial-line write-back amplification).
__global__ void fill_k(const int* __restrict__ src, const int* __restrict__ dst,
                       int* __restrict__ fillp, int* __restrict__ csr, int n_edges) {
    int e = blockIdx.x * blockDim.x + threadIdx.x;
    if (e < n_edges) {
        int d = dst[e];
        int s = src[e];
        int pos = atomicAdd(&fillp[d], 1);
        __builtin_nontemporal_store(s, csr + pos);
    }
}

// ------------------------------------------------------------ MFMA GEMM ----
template <int K, typename TIN>
__global__ void gemm_mfma_k(const TIN* __restrict__ X, const float* __restrict__ W,
                            const float* __restrict__ dinv, __half* __restrict__ Y,
                            int n_tiles) {
    __shared__ _Float16 Wl[K * 64];
    for (int i = threadIdx.x; i < K * 64; i += 256) Wl[i] = (_Float16)W[i];
    __syncthreads();

    const int lane = threadIdx.x & 63;
    const int wid  = threadIdx.x >> 6;   // 0..3
    const int col0 = lane & 15;
    const int kg   = lane >> 4;          // 0..3

    half8 bf[4][K / 32];
#pragma unroll
    for (int t = 0; t < 4; ++t)
#pragma unroll
        for (int s = 0; s < K / 32; ++s) {
            half8 b;
#pragma unroll
            for (int j = 0; j < 8; ++j) {
                int k = s * 32 + kg * 8 + j;
                b[j] = Wl[k * 64 + t * 16 + col0];
            }
            bf[t][s] = b;
        }

    const int nwaves = gridDim.x * 4;
    for (int tile = blockIdx.x * 4 + wid; tile < n_tiles; tile += nwaves) {
        const int row0 = tile * 16;
        const int arow = row0 + col0;

        half8 af[K / 32];
#pragma unroll
        for (int s = 0; s < K / 32; ++s) {
            if constexpr (sizeof(TIN) == 4) {
                const float* p = (const float*)X + (size_t)arow * K + s * 32 + kg * 8;
                f32x4 v0 = *(const f32x4*)p;
                f32x4 v1 = *(const f32x4*)(p + 4);
                half8 a;
#pragma unroll
                for (int j = 0; j < 4; ++j) { a[j] = (_Float16)v0[j]; a[4 + j] = (_Float16)v1[j]; }
                af[s] = a;
            } else {
                const __half* p = (const __half*)X + (size_t)arow * K + s * 32 + kg * 8;
                af[s] = *(const half8*)p;
            }
        }

        f32x4 acc[4];
#pragma unroll
        for (int t = 0; t < 4; ++t) acc[t] = (f32x4){0.f, 0.f, 0.f, 0.f};
#pragma unroll
        for (int s = 0; s < K / 32; ++s)
#pragma unroll
            for (int t = 0; t < 4; ++t)
                acc[t] = __builtin_amdgcn_mfma_f32_16x16x32_f16(af[s], bf[t][s], acc[t], 0, 0, 0);

        float dv[4];
#pragma unroll
        for (int r = 0; r < 4; ++r) dv[r] = dinv[row0 + kg * 4 + r];
#pragma unroll
        for (int t = 0; t < 4; ++t)
#pragma unroll
            for (int r = 0; r < 4; ++r) {
                int row = row0 + kg * 4 + r;
                Y[(size_t)row * 64 + t * 16 + col0] = __float2half(acc[t][r] * dv[r]);
            }
    }
}

// --------------------------------------------------------------- gather -----
__global__ void gather_k(const float2* __restrict__ H4, const float* __restrict__ dinv,
                         const int* __restrict__ rowptr, const int* __restrict__ csr,
                         const float* __restrict__ bias, uint2* __restrict__ out4) {
    int node = (blockIdx.x * blockDim.x + threadIdx.x) >> 6;
    if (node >= NN) return;
    const int lane = threadIdx.x & 63;
    const int q  = lane >> 4;      // quarter 0..3 (row group)
    const int fl = lane & 15;      // feature 4-pack (features 4fl..4fl+3)

    const int p0 = rowptr[node], p1 = rowptr[node + 1];

    float4 acc = make_float4(0.f, 0.f, 0.f, 0.f);
    if (q == 0) {                  // self-loop row
        float2 v = H4[(size_t)node * 16 + fl];
        const __half2* h = (const __half2*)&v;
        float2 a = __half22float2(h[0]), b = __half22float2(h[1]);
        acc.x += a.x; acc.y += a.y; acc.z += b.x; acc.w += b.y;
    }

    for (int base = p0; base < p1; base += 64) {
        int pos = base + lane;
        int cidx = (pos < p1) ? csr[pos] : 0;       // one coalesced read / chunk
        int m = p1 - base; if (m > 64) m = 64;
        int jmax = (m + 3) >> 2;                    // wave-uniform trip count
#pragma unroll 4
        for (int j = 0; j < jmax; ++j) {
            int nb = (j << 2) + q;                  // this quarter's neighbor slot
            int s = __shfl(cidx, nb, 64);           // all 64 lanes execute
            if (nb < m) {
                float2 v = H4[(size_t)s * 16 + fl];
                const __half2* h = (const __half2*)&v;
                float2 a = __half22float2(h[0]), b = __half22float2(h[1]);
                acc.x += a.x; acc.y += a.y; acc.z += b.x; acc.w += b.y;
            }
        }
    }

    // combine the 4 quarters
    acc.x += __shfl_xor(acc.x, 16, 64); acc.y += __shfl_xor(acc.y, 16, 64);
    acc.z += __shfl_xor(acc.z, 16, 64); acc.w += __shfl_xor(acc.w, 16, 64);
    acc.x += __shfl_xor(acc.x, 32, 64); acc.y += __shfl_xor(acc.y, 32, 64);
    acc.z += __shfl_xor(acc.z, 32, 64); acc.w += __shfl_xor(acc.w, 32, 64);

    if (q == 0) {
        float di = dinv[node];
        float4 b = ((const float4*)bias)[fl];
        float vx = fmaxf(fmaf(acc.x, di, b.x), 0.f);
        float vy = fmaxf(fmaf(acc.y, di, b.y), 0.f);
        float vz = fmaxf(fmaf(acc.z, di, b.z), 0.f);
        float vw = fmaxf(fmaf(acc.w, di, b.w), 0.f);
        __half2 lo = __floats2half2_rn(vx, vy), hi = __floats2half2_rn(vz, vw);
        uint2 o; o.x = *(const uint*)&lo; o.y = *(const uint*)&hi;
        out4[(size_t)node * 16 + fl] = o;
    }
}

// ------------------------------------------------------------- head ---------
__global__ void head_k(const __half2* __restrict__ H2, const float* __restrict__ W3,
                       const float* __restrict__ b3, float* __restrict__ out) {
    int wave = (blockIdx.x * blockDim.x + threadIdx.x) >> 6;
    const int lane = threadIdx.x & 63;
    const int half = lane >> 5;
    const int fl   = lane & 31;
    int node = wave * 2 + half;
    if (node >= NN) return;
    float2 h = __half22float2(H2[(size_t)node * 32 + fl]);
    float2 w = ((const float2*)W3)[fl];
    float v = h.x * w.x + h.y * w.y;
#pragma unroll
    for (int off = 16; off > 0; off >>= 1) v += __shfl_xor(v, off, 64);
    if (fl == 0) out[node] = v + b3[0];
}

// ---------------------------------------------------------------------------
extern "C" void kernel_launch(void* const* d_in, const int* in_sizes, int n_in,
                              void* d_out, int out_size, void* d_ws, size_t ws_size,
                              hipStream_t stream) {
    const float* x   = (const float*)d_in[0];
    const int*   ei  = (const int*)d_in[1];
    const float* W1  = (const float*)d_in[2];
    const float* b1  = (const float*)d_in[3];
    const float* W2  = (const float*)d_in[4];
    const float* b2  = (const float*)d_in[5];
    const float* W3  = (const float*)d_in[6];
    const float* b3  = (const float*)d_in[7];
    float* out = (float*)d_out;

    const int E = in_sizes[1] / 2;
    const int* src = ei;
    const int* dst = ei + E;

    // workspace layout (4B units):
    // dinv[N] | cnt[N] | excl[N] | rowptr[N+1] | fill[N] | bsum[512] | csr[E]
    // | bufA (N*64 fp16) | bufB (same)
    float* dinv  = (float*)d_ws;
    int* cnt     = (int*)(dinv + NN);
    int* excl    = cnt + NN;
    int* rowptr  = excl + NN;
    int* fillp   = rowptr + NN + 1;
    int* bsum    = fillp + NN;
    int* csr     = bsum + 512;
    __half* bufA = (__half*)(csr + E);
    __half* bufB = bufA + (size_t)NN * EMB;

    const int B = 256;
    const int gE  = (E + B - 1) / B;           // per-edge, one pass
    const int gNw = (NN * 64 + B - 1) / B;     // one wave per node
    const int gNh = (NN + 7) / 8;              // head: 8 nodes per block
    const int nb  = (NN + SCAN_B - 1) / SCAN_B;
    const int nTiles = NN / 16;                // 6250 exact
    const int gGemm = (nTiles + 3) / 4;        // 4 waves per block

    // ---- CSR build ----
    hipMemsetAsync(cnt, 0, NN * sizeof(int), stream);
    cnt_count_k<<<gE, B, 0, stream>>>(dst, cnt, E);
    scan1_k<<<nb, SCAN_B, 0, stream>>>(cnt, excl, bsum, dinv, NN);
    scan2_k<<<1, 512, 0, stream>>>(bsum, nb);
    scan3_k<<<nb, SCAN_B, 0, stream>>>(excl, bsum, rowptr, fillp, NN, E);
    fill_k<<<gE, B, 0, stream>>>(src, dst, fillp, csr, E);

    // ---- layer 1 ----
    gemm_mfma_k<FIN, float><<<gGemm, B, 0, stream>>>(x, W1, dinv, bufA, nTiles);
    gather_k<<<gNw, B, 0, stream>>>((const float2*)bufA, dinv, rowptr, csr, b1,
                                    (uint2*)bufB);

    // ---- layer 2 ----
    gemm_mfma_k<EMB, __half><<<gGemm, B, 0, stream>>>(bufB, W2, dinv, bufA, nTiles);
    gather_k<<<gNw, B, 0, stream>>>((const float2*)bufA, dinv, rowptr, csr, b2,
                                    (uint2*)bufB);

    // ---- head ----
    head_k<<<gNh, B, 0, stream>>>((const __half2*)bufB, W3, b3, out);
}

// Round 10
// 289.016 us; speedup vs baseline: 1.2570x; 1.2570x over previous
//
#include <hip/hip_runtime.h>
#include <hip/hip_bf16.h>
#include <hip/hip_fp16.h>

#define NN 100000     // nodes
#define FIN 128
#define EMB 64
#define SCAN_B 256
#define BW_SHIFT 8                          // bucket = dst >> 8  (256 nodes)
#define NB_BUCKET ((NN + 255) / 256)        // 391

using half8 = __attribute__((ext_vector_type(8))) _Float16;
using f32x4 = __attribute__((ext_vector_type(4))) float;

// ---------------------------------------------------------------- degree ----
__global__ void cnt_count_k(const int* __restrict__ dst, int* __restrict__ cnt, int n_edges) {
    int e = blockIdx.x * blockDim.x + threadIdx.x;
    if (e < n_edges) atomicAdd(&cnt[dst[e]], 1);
}

// ---------------------------------------------------------------- scan ------
__global__ void scan1_k(const int* __restrict__ cnt, int* __restrict__ excl,
                        int* __restrict__ bsum, float* __restrict__ dinv, int n) {
    __shared__ int tmp[SCAN_B];
    int tid = threadIdx.x;
    int i = blockIdx.x * SCAN_B + tid;
    int v = (i < n) ? cnt[i] : 0;
    if (i < n) dinv[i] = rsqrtf((float)(v + 1));   // +1 self-loop
    tmp[tid] = v; __syncthreads();
    for (int off = 1; off < SCAN_B; off <<= 1) {
        int t = (tid >= off) ? tmp[tid - off] : 0; __syncthreads();
        tmp[tid] += t; __syncthreads();
    }
    if (i < n) excl[i] = tmp[tid] - v;
    if (tid == SCAN_B - 1) bsum[blockIdx.x] = tmp[tid];
}

__global__ void scan2_k(int* __restrict__ bsum, int nb) {   // single block, nb<=512
    __shared__ int tmp[512];
    int tid = threadIdx.x;
    int v = (tid < nb) ? bsum[tid] : 0;
    tmp[tid] = v; __syncthreads();
    for (int off = 1; off < 512; off <<= 1) {
        int t = (tid >= off) ? tmp[tid - off] : 0; __syncthreads();
        tmp[tid] += t; __syncthreads();
    }
    if (tid < nb) bsum[tid] = tmp[tid] - v;
}

// writes rowptr, per-node fill cursors, and per-bucket cursors
__global__ void scan3_k(const int* __restrict__ excl, const int* __restrict__ bsum,
                        int* __restrict__ rowptr, int* __restrict__ fill,
                        int* __restrict__ bcur, int n, int n_edges) {
    int i = blockIdx.x * SCAN_B + threadIdx.x;
    if (i < n) {
        int r = excl[i] + bsum[blockIdx.x];
        rowptr[i] = r;
        fill[i] = r;
        if ((i & 255) == 0) bcur[i >> BW_SHIFT] = r;
    }
    if (i == 0) rowptr[n] = n_edges;
}

// ------------------------------------------------------- pass A: bin sort ---
// Per 4096-edge chunk: LDS counting sort by 256-node dst-bucket, one global
// cursor atomic per (bucket,chunk), then contiguous-run writes of (dst,src)
// pairs. No wide random scatter anywhere.
__global__ void binsort_k(const int* __restrict__ src, const int* __restrict__ dst,
                          int* __restrict__ bcur, uint2* __restrict__ pairs, int n_edges) {
    __shared__ uint2 sorted[4096];
    __shared__ int lcnt[NB_BUCKET];
    __shared__ int loff[NB_BUCKET];
    __shared__ int lpos[NB_BUCKET];
    __shared__ int gbase[NB_BUCKET];
    const int tid  = threadIdx.x;
    const int lane = tid & 63;

    for (int chunk = blockIdx.x; chunk * 4096 < n_edges; chunk += gridDim.x) {
        for (int i = tid; i < NB_BUCKET; i += 256) lcnt[i] = 0;
        __syncthreads();

        const int ebase = chunk * 4096;
        const int nval  = min(4096, n_edges - ebase);
        int d[16], s[16];
#pragma unroll
        for (int j = 0; j < 16; ++j) {
            int k = j * 256 + tid;
            if (k < nval) {
                int e = ebase + k;
                d[j] = dst[e]; s[j] = src[e];
                atomicAdd(&lcnt[d[j] >> BW_SHIFT], 1);
            } else d[j] = -1;
        }
        __syncthreads();

        // exclusive scan of lcnt (wave 0, shfl segments + carry)
        if (tid < 64) {
            int carry = 0;
            for (int seg = 0; seg < (NB_BUCKET + 63) / 64; ++seg) {
                int i = seg * 64 + lane;
                int v = (i < NB_BUCKET) ? lcnt[i] : 0;
                int incl = v;
                for (int off = 1; off < 64; off <<= 1) {
                    int idx = lane >= off ? lane - off : lane;
                    int t = __shfl(incl, idx, 64);
                    if (lane >= off) incl += t;
                }
                if (i < NB_BUCKET) loff[i] = incl - v + carry;
                carry += __shfl(incl, 63, 64);
            }
        }
        __syncthreads();

        for (int i = tid; i < NB_BUCKET; i += 256) {
            lpos[i] = loff[i];
            int n = lcnt[i];
            gbase[i] = n ? atomicAdd(&bcur[i], n) : 0;
        }
        __syncthreads();

#pragma unroll
        for (int j = 0; j < 16; ++j) {
            if (d[j] >= 0) {
                int b = d[j] >> BW_SHIFT;
                int slot = atomicAdd(&lpos[b], 1);
                sorted[slot] = make_uint2((unsigned)d[j], (unsigned)s[j]);
            }
        }
        __syncthreads();

        for (int i = tid; i < nval; i += 256) {
            uint2 p = sorted[i];
            int b = (int)(p.x >> BW_SHIFT);
            pairs[gbase[b] + (i - loff[b])] = p;       // ~10-entry contiguous runs
        }
        __syncthreads();
    }
}

// ------------------------------------------------- pass B: windowed fill ----
// One block per bucket: csr writes confined to a ~16KB L2-resident window.
__global__ void scatter_fill_k(const uint2* __restrict__ pairs, const int* __restrict__ rowptr,
                               int* __restrict__ fillp, int* __restrict__ csr) {
    const int b = blockIdx.x;
    const int lo = rowptr[b << BW_SHIFT];
    const int hiNode = min((b + 1) << BW_SHIFT, NN);
    const int hi = rowptr[hiNode];
#pragma unroll 4
    for (int i = lo + threadIdx.x; i < hi; i += blockDim.x) {
        uint2 p = pairs[i];
        int pos = atomicAdd(&fillp[p.x], 1);
        csr[pos] = (int)p.y;
    }
}

// ------------------------------------------------------------ MFMA GEMM ----
template <int K, typename TIN>
__global__ void gemm_mfma_k(const TIN* __restrict__ X, const float* __restrict__ W,
                            const float* __restrict__ dinv, __half* __restrict__ Y,
                            int n_tiles) {
    __shared__ _Float16 Wl[K * 64];
    for (int i = threadIdx.x; i < K * 64; i += 256) Wl[i] = (_Float16)W[i];
    __syncthreads();

    const int lane = threadIdx.x & 63;
    const int wid  = threadIdx.x >> 6;   // 0..3
    const int col0 = lane & 15;
    const int kg   = lane >> 4;          // 0..3

    half8 bf[4][K / 32];
#pragma unroll
    for (int t = 0; t < 4; ++t)
#pragma unroll
        for (int s = 0; s < K / 32; ++s) {
            half8 b;
#pragma unroll
            for (int j = 0; j < 8; ++j) {
                int k = s * 32 + kg * 8 + j;
                b[j] = Wl[k * 64 + t * 16 + col0];
            }
            bf[t][s] = b;
        }

    const int nwaves = gridDim.x * 4;
    for (int tile = blockIdx.x * 4 + wid; tile < n_tiles; tile += nwaves) {
        const int row0 = tile * 16;
        const int arow = row0 + col0;

        half8 af[K / 32];
#pragma unroll
        for (int s = 0; s < K / 32; ++s) {
            if constexpr (sizeof(TIN) == 4) {
                const float* p = (const float*)X + (size_t)arow * K + s * 32 + kg * 8;
                f32x4 v0 = *(const f32x4*)p;
                f32x4 v1 = *(const f32x4*)(p + 4);
                half8 a;
#pragma unroll
                for (int j = 0; j < 4; ++j) { a[j] = (_Float16)v0[j]; a[4 + j] = (_Float16)v1[j]; }
                af[s] = a;
            } else {
                const __half* p = (const __half*)X + (size_t)arow * K + s * 32 + kg * 8;
                af[s] = *(const half8*)p;
            }
        }

        f32x4 acc[4];
#pragma unroll
        for (int t = 0; t < 4; ++t) acc[t] = (f32x4){0.f, 0.f, 0.f, 0.f};
#pragma unroll
        for (int s = 0; s < K / 32; ++s)
#pragma unroll
            for (int t = 0; t < 4; ++t)
                acc[t] = __builtin_amdgcn_mfma_f32_16x16x32_f16(af[s], bf[t][s], acc[t], 0, 0, 0);

        float dv[4];
#pragma unroll
        for (int r = 0; r < 4; ++r) dv[r] = dinv[row0 + kg * 4 + r];
#pragma unroll
        for (int t = 0; t < 4; ++t)
#pragma unroll
            for (int r = 0; r < 4; ++r) {
                int row = row0 + kg * 4 + r;
                Y[(size_t)row * 64 + t * 16 + col0] = __float2half(acc[t][r] * dv[r]);
            }
    }
}

// --------------------------------------------------------------- gather -----
__global__ void gather_k(const float2* __restrict__ H4, const float* __restrict__ dinv,
                         const int* __restrict__ rowptr, const int* __restrict__ csr,
                         const float* __restrict__ bias, uint2* __restrict__ out4) {
    int node = (blockIdx.x * blockDim.x + threadIdx.x) >> 6;
    if (node >= NN) return;
    const int lane = threadIdx.x & 63;
    const int q  = lane >> 4;      // quarter 0..3 (row group)
    const int fl = lane & 15;      // feature 4-pack (features 4fl..4fl+3)

    const int p0 = rowptr[node], p1 = rowptr[node + 1];

    float4 acc = make_float4(0.f, 0.f, 0.f, 0.f);
    if (q == 0) {                  // self-loop row
        float2 v = H4[(size_t)node * 16 + fl];
        const __half2* h = (const __half2*)&v;
        float2 a = __half22float2(h[0]), b = __half22float2(h[1]);
        acc.x += a.x; acc.y += a.y; acc.z += b.x; acc.w += b.y;
    }

    for (int base = p0; base < p1; base += 64) {
        int pos = base + lane;
        int cidx = (pos < p1) ? csr[pos] : 0;       // one coalesced read / chunk
        int m = p1 - base; if (m > 64) m = 64;
        int jmax = (m + 3) >> 2;                    // wave-uniform trip count
#pragma unroll 4
        for (int j = 0; j < jmax; ++j) {
            int nb = (j << 2) + q;                  // this quarter's neighbor slot
            int s = __shfl(cidx, nb, 64);           // all 64 lanes execute
            if (nb < m) {
                float2 v = H4[(size_t)s * 16 + fl];
                const __half2* h = (const __half2*)&v;
                float2 a = __half22float2(h[0]), b = __half22float2(h[1]);
                acc.x += a.x; acc.y += a.y; acc.z += b.x; acc.w += b.y;
            }
        }
    }

    // combine the 4 quarters
    acc.x += __shfl_xor(acc.x, 16, 64); acc.y += __shfl_xor(acc.y, 16, 64);
    acc.z += __shfl_xor(acc.z, 16, 64); acc.w += __shfl_xor(acc.w, 16, 64);
    acc.x += __shfl_xor(acc.x, 32, 64); acc.y += __shfl_xor(acc.y, 32, 64);
    acc.z += __shfl_xor(acc.z, 32, 64); acc.w += __shfl_xor(acc.w, 32, 64);

    if (q == 0) {
        float di = dinv[node];
        float4 b = ((const float4*)bias)[fl];
        float vx = fmaxf(fmaf(acc.x, di, b.x), 0.f);
        float vy = fmaxf(fmaf(acc.y, di, b.y), 0.f);
        float vz = fmaxf(fmaf(acc.z, di, b.z), 0.f);
        float vw = fmaxf(fmaf(acc.w, di, b.w), 0.f);
        __half2 lo = __floats2half2_rn(vx, vy), hi = __floats2half2_rn(vz, vw);
        uint2 o; o.x = *(const uint*)&lo; o.y = *(const uint*)&hi;
        out4[(size_t)node * 16 + fl] = o;
    }
}

// ------------------------------------------------------------- head ---------
__global__ void head_k(const __half2* __restrict__ H2, const float* __restrict__ W3,
                       const float* __restrict__ b3, float* __restrict__ out) {
    int wave = (blockIdx.x * blockDim.x + threadIdx.x) >> 6;
    const int lane = threadIdx.x & 63;
    const int half = lane >> 5;
    const int fl   = lane & 31;
    int node = wave * 2 + half;
    if (node >= NN) return;
    float2 h = __half22float2(H2[(size_t)node * 32 + fl]);
    float2 w = ((const float2*)W3)[fl];
    float v = h.x * w.x + h.y * w.y;
#pragma unroll
    for (int off = 16; off > 0; off >>= 1) v += __shfl_xor(v, off, 64);
    if (fl == 0) out[node] = v + b3[0];
}

// ---------------------------------------------------------------------------
extern "C" void kernel_launch(void* const* d_in, const int* in_sizes, int n_in,
                              void* d_out, int out_size, void* d_ws, size_t ws_size,
                              hipStream_t stream) {
    const float* x   = (const float*)d_in[0];
    const int*   ei  = (const int*)d_in[1];
    const float* W1  = (const float*)d_in[2];
    const float* b1  = (const float*)d_in[3];
    const float* W2  = (const float*)d_in[4];
    const float* b2  = (const float*)d_in[5];
    const float* W3  = (const float*)d_in[6];
    const float* b3  = (const float*)d_in[7];
    float* out = (float*)d_out;

    const int E = in_sizes[1] / 2;
    const int* src = ei;
    const int* dst = ei + E;

    // workspace layout (4B units):
    // dinv[N] | cnt[N] | excl[N] | rowptr[N+1] | fillp[N] | bsum[512] |
    // bcur[512] | csr[E] | bufA (N*64 fp16) | bufB (same)
    // pairs[E] (8B each) overlays bufA/bufB during CSR build only.
    float* dinv  = (float*)d_ws;
    int* cnt     = (int*)(dinv + NN);
    int* excl    = cnt + NN;
    int* rowptr  = excl + NN;
    int* fillp   = rowptr + NN + 1;
    int* bsum    = fillp + NN;
    int* bcur    = bsum + 512;
    int* csr     = bcur + 512;
    __half* bufA = (__half*)(csr + E);
    __half* bufB = bufA + (size_t)NN * EMB;
    uint2* pairs = (uint2*)bufA;               // overlay, CSR-build phase only

    const int B = 256;
    const int gE  = (E + B - 1) / B;
    const int gNw = (NN * 64 + B - 1) / B;     // one wave per node
    const int gNh = (NN + 7) / 8;              // head: 8 nodes per block
    const int nb  = (NN + SCAN_B - 1) / SCAN_B;
    const int nTiles = NN / 16;                // 6250 exact
    const int gGemm = (nTiles + 3) / 4;        // 4 waves per block
    const int gBin  = (E + 4095) / 4096;       // one chunk per block

    // ---- CSR build ----
    hipMemsetAsync(cnt, 0, NN * sizeof(int), stream);
    cnt_count_k<<<gE, B, 0, stream>>>(dst, cnt, E);
    scan1_k<<<nb, SCAN_B, 0, stream>>>(cnt, excl, bsum, dinv, NN);
    scan2_k<<<1, 512, 0, stream>>>(bsum, nb);
    scan3_k<<<nb, SCAN_B, 0, stream>>>(excl, bsum, rowptr, fillp, bcur, NN, E);
    binsort_k<<<gBin, B, 0, stream>>>(src, dst, bcur, pairs, E);
    scatter_fill_k<<<NB_BUCKET, 1024, 0, stream>>>(pairs, rowptr, fillp, csr);

    // ---- layer 1 ----
    gemm_mfma_k<FIN, float><<<gGemm, B, 0, stream>>>(x, W1, dinv, bufA, nTiles);
    gather_k<<<gNw, B, 0, stream>>>((const float2*)bufA, dinv, rowptr, csr, b1,
                                    (uint2*)bufB);

    // ---- layer 2 ----
    gemm_mfma_k<EMB, __half><<<gGemm, B, 0, stream>>>(bufB, W2, dinv, bufA, nTiles);
    gather_k<<<gNw, B, 0, stream>>>((const float2*)bufA, dinv, rowptr, csr, b2,
                                    (uint2*)bufB);

    // ---- head ----
    head_k<<<gNh, B, 0, stream>>>((const __half2*)bufB, W3, b3, out);
}

// Round 11
// 218.858 us; speedup vs baseline: 1.6599x; 1.3206x over previous
//
#include <hip/hip_runtime.h>
#include <hip/hip_bf16.h>
#include <hip/hip_fp16.h>

#define NN 100000     // nodes
#define FIN 128
#define EMB 64
#define BW_SHIFT 8                          // bucket = dst >> 8  (256 nodes)
#define NB_BUCKET ((NN + 255) / 256)        // 391

using half8 = __attribute__((ext_vector_type(8))) _Float16;
using f32x4 = __attribute__((ext_vector_type(4))) float;

// ----------------------------------------------------- bucket histogram -----
// LDS-binned: per-edge atomics hit LDS; only 391 global atomics per block.
__global__ void bucket_cnt_k(const int* __restrict__ dst, int* __restrict__ bbase,
                             int n_edges) {
    __shared__ int bcnt[NB_BUCKET];
    for (int i = threadIdx.x; i < NB_BUCKET; i += 256) bcnt[i] = 0;
    __syncthreads();
    for (int e = blockIdx.x * 256 + threadIdx.x; e < n_edges; e += gridDim.x * 256)
        atomicAdd(&bcnt[dst[e] >> BW_SHIFT], 1);
    __syncthreads();
    for (int i = threadIdx.x; i < NB_BUCKET; i += 256) {
        int v = bcnt[i];
        if (v) atomicAdd(&bbase[i], v);
    }
}

// ----------------------------------------------------- bucket scan ----------
// single block: exclusive scan of 391 bucket counts -> bbase & bcur
__global__ void bscan_k(int* __restrict__ bbase, int* __restrict__ bcur, int n_edges) {
    __shared__ int tmp[512];
    int tid = threadIdx.x;
    int v = (tid < NB_BUCKET) ? bbase[tid] : 0;
    tmp[tid] = v; __syncthreads();
    for (int off = 1; off < 512; off <<= 1) {
        int t = (tid >= off) ? tmp[tid - off] : 0; __syncthreads();
        tmp[tid] += t; __syncthreads();
    }
    int excl = tmp[tid] - v;
    if (tid < NB_BUCKET) { bbase[tid] = excl; bcur[tid] = excl; }
    if (tid == NB_BUCKET - 1) bbase[NB_BUCKET] = n_edges;
}

// ------------------------------------------------------- pass A: bin sort ---
// Per 4096-edge chunk: LDS counting sort by 256-node dst-bucket, one global
// cursor atomic per (bucket,chunk), then contiguous-run writes of (dst,src).
__global__ void binsort_k(const int* __restrict__ src, const int* __restrict__ dst,
                          int* __restrict__ bcur, uint2* __restrict__ pairs, int n_edges) {
    __shared__ uint2 sorted[4096];
    __shared__ int lcnt[NB_BUCKET];
    __shared__ int loff[NB_BUCKET];
    __shared__ int lpos[NB_BUCKET];
    __shared__ int gbase[NB_BUCKET];
    const int tid  = threadIdx.x;
    const int lane = tid & 63;

    for (int chunk = blockIdx.x; chunk * 4096 < n_edges; chunk += gridDim.x) {
        for (int i = tid; i < NB_BUCKET; i += 256) lcnt[i] = 0;
        __syncthreads();

        const int ebase = chunk * 4096;
        const int nval  = min(4096, n_edges - ebase);
        int d[16], s[16];
#pragma unroll
        for (int j = 0; j < 16; ++j) {
            int k = j * 256 + tid;
            if (k < nval) {
                int e = ebase + k;
                d[j] = dst[e]; s[j] = src[e];
                atomicAdd(&lcnt[d[j] >> BW_SHIFT], 1);
            } else d[j] = -1;
        }
        __syncthreads();

        // exclusive scan of lcnt (wave 0, shfl segments + carry)
        if (tid < 64) {
            int carry = 0;
            for (int seg = 0; seg < (NB_BUCKET + 63) / 64; ++seg) {
                int i = seg * 64 + lane;
                int v = (i < NB_BUCKET) ? lcnt[i] : 0;
                int incl = v;
                for (int off = 1; off < 64; off <<= 1) {
                    int idx = lane >= off ? lane - off : lane;
                    int t = __shfl(incl, idx, 64);
                    if (lane >= off) incl += t;
                }
                if (i < NB_BUCKET) loff[i] = incl - v + carry;
                carry += __shfl(incl, 63, 64);
            }
        }
        __syncthreads();

        for (int i = tid; i < NB_BUCKET; i += 256) {
            lpos[i] = loff[i];
            int n = lcnt[i];
            gbase[i] = n ? atomicAdd(&bcur[i], n) : 0;
        }
        __syncthreads();

#pragma unroll
        for (int j = 0; j < 16; ++j) {
            if (d[j] >= 0) {
                int b = d[j] >> BW_SHIFT;
                int slot = atomicAdd(&lpos[b], 1);
                sorted[slot] = make_uint2((unsigned)d[j], (unsigned)s[j]);
            }
        }
        __syncthreads();

        for (int i = tid; i < nval; i += 256) {
            uint2 p = sorted[i];
            int b = (int)(p.x >> BW_SHIFT);
            pairs[gbase[b] + (i - loff[b])] = p;       // ~10-entry contiguous runs
        }
        __syncthreads();
    }
}

// -------------------------------------------- pass B: per-bucket CSR build --
// One block per bucket. ALL per-edge atomics are LDS. Writes rowptr, dinv,
// and csr (confined to the bucket's contiguous ~16KB window).
__global__ void bucket_build_k(const uint2* __restrict__ pairs, const int* __restrict__ bbase,
                               int* __restrict__ rowptr, float* __restrict__ dinv,
                               int* __restrict__ csr, int n_edges) {
    __shared__ int ndeg[256];
    __shared__ int nexcl[256];
    __shared__ int ncur[256];
    const int b   = blockIdx.x;
    const int tid = threadIdx.x;
    const int lo = bbase[b], hi = bbase[b + 1];
    const int n0 = b << BW_SHIFT;
    const int nn = min(256, NN - n0);

    ndeg[tid] = 0;
    __syncthreads();
    for (int i = lo + tid; i < hi; i += 256)
        atomicAdd(&ndeg[(int)pairs[i].x - n0], 1);
    __syncthreads();

    // block scan (Hillis-Steele over 256)
    int v = ndeg[tid];
    nexcl[tid] = v;
    __syncthreads();
    for (int off = 1; off < 256; off <<= 1) {
        int t = (tid >= off) ? nexcl[tid - off] : 0;
        __syncthreads();
        nexcl[tid] += t;
        __syncthreads();
    }
    int excl = nexcl[tid] - v;

    if (tid < nn) {
        rowptr[n0 + tid] = lo + excl;
        dinv[n0 + tid] = rsqrtf((float)(v + 1));   // +1 self-loop
    }
    if (b == NB_BUCKET - 1 && tid == 0) rowptr[NN] = n_edges;
    ncur[tid] = lo + excl;
    __syncthreads();

    for (int i = lo + tid; i < hi; i += 256) {
        uint2 p = pairs[i];
        int pos = atomicAdd(&ncur[(int)p.x - n0], 1);
        csr[pos] = (int)p.y;
    }
}

// ------------------------------------------------------------ MFMA GEMM ----
template <int K, typename TIN>
__global__ void gemm_mfma_k(const TIN* __restrict__ X, const float* __restrict__ W,
                            const float* __restrict__ dinv, __half* __restrict__ Y,
                            int n_tiles) {
    __shared__ _Float16 Wl[K * 64];
    for (int i = threadIdx.x; i < K * 64; i += 256) Wl[i] = (_Float16)W[i];
    __syncthreads();

    const int lane = threadIdx.x & 63;
    const int wid  = threadIdx.x >> 6;   // 0..3
    const int col0 = lane & 15;
    const int kg   = lane >> 4;          // 0..3

    half8 bf[4][K / 32];
#pragma unroll
    for (int t = 0; t < 4; ++t)
#pragma unroll
        for (int s = 0; s < K / 32; ++s) {
            half8 b;
#pragma unroll
            for (int j = 0; j < 8; ++j) {
                int k = s * 32 + kg * 8 + j;
                b[j] = Wl[k * 64 + t * 16 + col0];
            }
            bf[t][s] = b;
        }

    const int nwaves = gridDim.x * 4;
    for (int tile = blockIdx.x * 4 + wid; tile < n_tiles; tile += nwaves) {
        const int row0 = tile * 16;
        const int arow = row0 + col0;

        half8 af[K / 32];
#pragma unroll
        for (int s = 0; s < K / 32; ++s) {
            if constexpr (sizeof(TIN) == 4) {
                const float* p = (const float*)X + (size_t)arow * K + s * 32 + kg * 8;
                f32x4 v0 = *(const f32x4*)p;
                f32x4 v1 = *(const f32x4*)(p + 4);
                half8 a;
#pragma unroll
                for (int j = 0; j < 4; ++j) { a[j] = (_Float16)v0[j]; a[4 + j] = (_Float16)v1[j]; }
                af[s] = a;
            } else {
                const __half* p = (const __half*)X + (size_t)arow * K + s * 32 + kg * 8;
                af[s] = *(const half8*)p;
            }
        }

        f32x4 acc[4];
#pragma unroll
        for (int t = 0; t < 4; ++t) acc[t] = (f32x4){0.f, 0.f, 0.f, 0.f};
#pragma unroll
        for (int s = 0; s < K / 32; ++s)
#pragma unroll
            for (int t = 0; t < 4; ++t)
                acc[t] = __builtin_amdgcn_mfma_f32_16x16x32_f16(af[s], bf[t][s], acc[t], 0, 0, 0);

        float dv[4];
#pragma unroll
        for (int r = 0; r < 4; ++r) dv[r] = dinv[row0 + kg * 4 + r];
#pragma unroll
        for (int t = 0; t < 4; ++t)
#pragma unroll
            for (int r = 0; r < 4; ++r) {
                int row = row0 + kg * 4 + r;
                Y[(size_t)row * 64 + t * 16 + col0] = __float2half(acc[t][r] * dv[r]);
            }
    }
}

// --------------------------------------------------------------- gather -----
__global__ void gather_k(const float2* __restrict__ H4, const float* __restrict__ dinv,
                         const int* __restrict__ rowptr, const int* __restrict__ csr,
                         const float* __restrict__ bias, uint2* __restrict__ out4) {
    int node = (blockIdx.x * blockDim.x + threadIdx.x) >> 6;
    if (node >= NN) return;
    const int lane = threadIdx.x & 63;
    const int q  = lane >> 4;      // quarter 0..3 (row group)
    const int fl = lane & 15;      // feature 4-pack (features 4fl..4fl+3)

    const int p0 = rowptr[node], p1 = rowptr[node + 1];

    float4 acc = make_float4(0.f, 0.f, 0.f, 0.f);
    if (q == 0) {                  // self-loop row
        float2 v = H4[(size_t)node * 16 + fl];
        const __half2* h = (const __half2*)&v;
        float2 a = __half22float2(h[0]), b = __half22float2(h[1]);
        acc.x += a.x; acc.y += a.y; acc.z += b.x; acc.w += b.y;
    }

    for (int base = p0; base < p1; base += 64) {
        int pos = base + lane;
        int cidx = (pos < p1) ? csr[pos] : 0;       // one coalesced read / chunk
        int m = p1 - base; if (m > 64) m = 64;
        int jmax = (m + 3) >> 2;                    // wave-uniform trip count
#pragma unroll 4
        for (int j = 0; j < jmax; ++j) {
            int nb = (j << 2) + q;                  // this quarter's neighbor slot
            int s = __shfl(cidx, nb, 64);           // all 64 lanes execute
            if (nb < m) {
                float2 v = H4[(size_t)s * 16 + fl];
                const __half2* h = (const __half2*)&v;
                float2 a = __half22float2(h[0]), b = __half22float2(h[1]);
                acc.x += a.x; acc.y += a.y; acc.z += b.x; acc.w += b.y;
            }
        }
    }

    // combine the 4 quarters
    acc.x += __shfl_xor(acc.x, 16, 64); acc.y += __shfl_xor(acc.y, 16, 64);
    acc.z += __shfl_xor(acc.z, 16, 64); acc.w += __shfl_xor(acc.w, 16, 64);
    acc.x += __shfl_xor(acc.x, 32, 64); acc.y += __shfl_xor(acc.y, 32, 64);
    acc.z += __shfl_xor(acc.z, 32, 64); acc.w += __shfl_xor(acc.w, 32, 64);

    if (q == 0) {
        float di = dinv[node];
        float4 b = ((const float4*)bias)[fl];
        float vx = fmaxf(fmaf(acc.x, di, b.x), 0.f);
        float vy = fmaxf(fmaf(acc.y, di, b.y), 0.f);
        float vz = fmaxf(fmaf(acc.z, di, b.z), 0.f);
        float vw = fmaxf(fmaf(acc.w, di, b.w), 0.f);
        __half2 lo = __floats2half2_rn(vx, vy), hi = __floats2half2_rn(vz, vw);
        uint2 o; o.x = *(const uint*)&lo; o.y = *(const uint*)&hi;
        out4[(size_t)node * 16 + fl] = o;
    }
}

// ------------------------------------------------------------- head ---------
__global__ void head_k(const __half2* __restrict__ H2, const float* __restrict__ W3,
                       const float* __restrict__ b3, float* __restrict__ out) {
    int wave = (blockIdx.x * blockDim.x + threadIdx.x) >> 6;
    const int lane = threadIdx.x & 63;
    const int half = lane >> 5;
    const int fl   = lane & 31;
    int node = wave * 2 + half;
    if (node >= NN) return;
    float2 h = __half22float2(H2[(size_t)node * 32 + fl]);
    float2 w = ((const float2*)W3)[fl];
    float v = h.x * w.x + h.y * w.y;
#pragma unroll
    for (int off = 16; off > 0; off >>= 1) v += __shfl_xor(v, off, 64);
    if (fl == 0) out[node] = v + b3[0];
}

// ---------------------------------------------------------------------------
extern "C" void kernel_launch(void* const* d_in, const int* in_sizes, int n_in,
                              void* d_out, int out_size, void* d_ws, size_t ws_size,
                              hipStream_t stream) {
    const float* x   = (const float*)d_in[0];
    const int*   ei  = (const int*)d_in[1];
    const float* W1  = (const float*)d_in[2];
    const float* b1  = (const float*)d_in[3];
    const float* W2  = (const float*)d_in[4];
    const float* b2  = (const float*)d_in[5];
    const float* W3  = (const float*)d_in[6];
    const float* b3  = (const float*)d_in[7];
    float* out = (float*)d_out;

    const int E = in_sizes[1] / 2;
    const int* src = ei;
    const int* dst = ei + E;

    // workspace layout (4B units):
    // dinv[N] | rowptr[N+1] | bbase[512] | bcur[512] | csr[E] | bufA | bufB
    // pairs[E] (8B) overlays bufA during CSR build only (E*8 == N*64*2 bytes).
    float* dinv  = (float*)d_ws;
    int* rowptr  = (int*)(dinv + NN);
    int* bbase   = rowptr + NN + 1;
    int* bcur    = bbase + 512;
    int* csr     = bcur + 512;
    __half* bufA = (__half*)(csr + E);
    __half* bufB = bufA + (size_t)NN * EMB;
    uint2* pairs = (uint2*)bufA;               // overlay, CSR-build phase only

    const int B = 256;
    const int gNw = (NN * 64 + B - 1) / B;     // one wave per node
    const int gNh = (NN + 7) / 8;              // head: 8 nodes per block
    const int nTiles = NN / 16;                // 6250 exact
    const int gGemm = (nTiles + 3) / 4;        // 4 waves per block
    const int gBin  = (E + 4095) / 4096;       // one chunk per block

    // ---- CSR build (no per-edge global atomics anywhere) ----
    hipMemsetAsync(bbase, 0, 512 * sizeof(int), stream);
    bucket_cnt_k<<<512, B, 0, stream>>>(dst, bbase, E);
    bscan_k<<<1, 512, 0, stream>>>(bbase, bcur, E);
    binsort_k<<<gBin, B, 0, stream>>>(src, dst, bcur, pairs, E);
    bucket_build_k<<<NB_BUCKET, B, 0, stream>>>(pairs, bbase, rowptr, dinv, csr, E);

    // ---- layer 1 ----
    gemm_mfma_k<FIN, float><<<gGemm, B, 0, stream>>>(x, W1, dinv, bufA, nTiles);
    gather_k<<<gNw, B, 0, stream>>>((const float2*)bufA, dinv, rowptr, csr, b1,
                                    (uint2*)bufB);

    // ---- layer 2 ----
    gemm_mfma_k<EMB, __half><<<gGemm, B, 0, stream>>>(bufB, W2, dinv, bufA, nTiles);
    gather_k<<<gNw, B, 0, stream>>>((const float2*)bufA, dinv, rowptr, csr, b2,
                                    (uint2*)bufB);

    // ---- head ----
    head_k<<<gNh, B, 0, stream>>>((const __half2*)bufB, W3, b3, out);
}

// Round 12
// 217.569 us; speedup vs baseline: 1.6697x; 1.0059x over previous
//
#include <hip/hip_runtime.h>
#include <hip/hip_bf16.h>
#include <hip/hip_fp16.h>

#define NN 100000     // nodes
#define FIN 128
#define EMB 64
#define BW_SHIFT 8                          // bucket = dst >> 8  (256 nodes)
#define NB_BUCKET ((NN + 255) / 256)        // 391

using half8 = __attribute__((ext_vector_type(8))) _Float16;
using f32x4 = __attribute__((ext_vector_type(4))) float;

#define BIN_LDS (4096 * 8 + 4 * NB_BUCKET * 4)     // 39024 B
#define GEMM_LDS (FIN * 64 * 2)                    // 16384 B
#define FUSED_LDS (BIN_LDS > GEMM_LDS ? BIN_LDS : GEMM_LDS)

// ----------------------------------------------------- bucket histogram -----
__global__ void bucket_cnt_k(const int* __restrict__ dst, int* __restrict__ bbase,
                             int n_edges) {
    __shared__ int bcnt[NB_BUCKET];
    for (int i = threadIdx.x; i < NB_BUCKET; i += 256) bcnt[i] = 0;
    __syncthreads();
    for (int e = blockIdx.x * 256 + threadIdx.x; e < n_edges; e += gridDim.x * 256)
        atomicAdd(&bcnt[dst[e] >> BW_SHIFT], 1);
    __syncthreads();
    for (int i = threadIdx.x; i < NB_BUCKET; i += 256) {
        int v = bcnt[i];
        if (v) atomicAdd(&bbase[i], v);
    }
}

// ----------------------------------------------------- bucket scan ----------
__global__ void bscan_k(int* __restrict__ bbase, int* __restrict__ bcur, int n_edges) {
    __shared__ int tmp[512];
    int tid = threadIdx.x;
    int v = (tid < NB_BUCKET) ? bbase[tid] : 0;
    tmp[tid] = v; __syncthreads();
    for (int off = 1; off < 512; off <<= 1) {
        int t = (tid >= off) ? tmp[tid - off] : 0; __syncthreads();
        tmp[tid] += t; __syncthreads();
    }
    int excl = tmp[tid] - v;
    if (tid < NB_BUCKET) { bbase[tid] = excl; bcur[tid] = excl; }
    if (tid == NB_BUCKET - 1) bbase[NB_BUCKET] = n_edges;
}

// ---------------------------------------- fused: binsort (A) || GEMM1 -------
// Blocks [0,nBin): LDS counting sort of (dst,src) by 256-node bucket.
// Blocks [nBin,..): MFMA GEMM h~ = x @ W1 (UNSCALED; dinv applied later in
// bucket_build, which is when dinv first exists). Independent work -> overlap.
__global__ void binsort_gemm_k(const int* __restrict__ src, const int* __restrict__ dst,
                               int* __restrict__ bcur, uint2* __restrict__ pairs,
                               int n_edges, int nBin,
                               const float* __restrict__ X, const float* __restrict__ W,
                               __half* __restrict__ Y, int n_tiles, int nGemm) {
    __shared__ __align__(16) char smraw[FUSED_LDS];
    const int tid = threadIdx.x;

    if (blockIdx.x < nBin) {
        // ---------------- binsort ----------------
        uint2* sorted = (uint2*)smraw;
        int* lcnt  = (int*)(smraw + 4096 * 8);
        int* loff  = lcnt + NB_BUCKET;
        int* lpos  = loff + NB_BUCKET;
        int* gbase = lpos + NB_BUCKET;
        const int lane = tid & 63;

        for (int chunk = blockIdx.x; chunk * 4096 < n_edges; chunk += nBin) {
            for (int i = tid; i < NB_BUCKET; i += 256) lcnt[i] = 0;
            __syncthreads();

            const int ebase = chunk * 4096;
            const int nval  = min(4096, n_edges - ebase);
            int d[16], s[16];
#pragma unroll
            for (int j = 0; j < 16; ++j) {
                int k = j * 256 + tid;
                if (k < nval) {
                    int e = ebase + k;
                    d[j] = dst[e]; s[j] = src[e];
                    atomicAdd(&lcnt[d[j] >> BW_SHIFT], 1);
                } else d[j] = -1;
            }
            __syncthreads();

            if (tid < 64) {                 // exclusive scan of lcnt
                int carry = 0;
                for (int seg = 0; seg < (NB_BUCKET + 63) / 64; ++seg) {
                    int i = seg * 64 + lane;
                    int v = (i < NB_BUCKET) ? lcnt[i] : 0;
                    int incl = v;
                    for (int off = 1; off < 64; off <<= 1) {
                        int idx = lane >= off ? lane - off : lane;
                        int t = __shfl(incl, idx, 64);
                        if (lane >= off) incl += t;
                    }
                    if (i < NB_BUCKET) loff[i] = incl - v + carry;
                    carry += __shfl(incl, 63, 64);
                }
            }
            __syncthreads();

            for (int i = tid; i < NB_BUCKET; i += 256) {
                lpos[i] = loff[i];
                int n = lcnt[i];
                gbase[i] = n ? atomicAdd(&bcur[i], n) : 0;
            }
            __syncthreads();

#pragma unroll
            for (int j = 0; j < 16; ++j) {
                if (d[j] >= 0) {
                    int b = d[j] >> BW_SHIFT;
                    int slot = atomicAdd(&lpos[b], 1);
                    sorted[slot] = make_uint2((unsigned)d[j], (unsigned)s[j]);
                }
            }
            __syncthreads();

            for (int i = tid; i < nval; i += 256) {
                uint2 p = sorted[i];
                int b = (int)(p.x >> BW_SHIFT);
                pairs[gbase[b] + (i - loff[b])] = p;
            }
            __syncthreads();
        }
    } else {
        // ---------------- GEMM1 (no dinv) ----------------
        _Float16* Wl = (_Float16*)smraw;
        for (int i = tid; i < FIN * 64; i += 256) Wl[i] = (_Float16)W[i];
        __syncthreads();

        const int lane = tid & 63;
        const int wid  = tid >> 6;
        const int col0 = lane & 15;
        const int kg   = lane >> 4;

        half8 bf[4][FIN / 32];
#pragma unroll
        for (int t = 0; t < 4; ++t)
#pragma unroll
            for (int s = 0; s < FIN / 32; ++s) {
                half8 b;
#pragma unroll
                for (int j = 0; j < 8; ++j)
                    b[j] = Wl[(s * 32 + kg * 8 + j) * 64 + t * 16 + col0];
                bf[t][s] = b;
            }

        const int gb = blockIdx.x - nBin;
        for (int tile = gb * 4 + wid; tile < n_tiles; tile += nGemm * 4) {
            const int arow = tile * 16 + col0;
            half8 af[FIN / 32];
#pragma unroll
            for (int s = 0; s < FIN / 32; ++s) {
                const float* p = X + (size_t)arow * FIN + s * 32 + kg * 8;
                f32x4 v0 = *(const f32x4*)p;
                f32x4 v1 = *(const f32x4*)(p + 4);
                half8 a;
#pragma unroll
                for (int j = 0; j < 4; ++j) { a[j] = (_Float16)v0[j]; a[4 + j] = (_Float16)v1[j]; }
                af[s] = a;
            }
            f32x4 acc[4];
#pragma unroll
            for (int t = 0; t < 4; ++t) acc[t] = (f32x4){0.f, 0.f, 0.f, 0.f};
#pragma unroll
            for (int s = 0; s < FIN / 32; ++s)
#pragma unroll
                for (int t = 0; t < 4; ++t)
                    acc[t] = __builtin_amdgcn_mfma_f32_16x16x32_f16(af[s], bf[t][s], acc[t], 0, 0, 0);
#pragma unroll
            for (int t = 0; t < 4; ++t)
#pragma unroll
                for (int r = 0; r < 4; ++r) {
                    int row = tile * 16 + kg * 4 + r;
                    Y[(size_t)row * 64 + t * 16 + col0] = __float2half(acc[t][r]);
                }
        }
    }
}

// -------------------------------------------- pass B: per-bucket CSR build --
// One block per bucket. LDS-only per-edge atomics. Also computes dinv and
// scales this bucket's h~ rows by dinv (h~ produced unscaled by fused GEMM1).
__global__ void bucket_build_k(const uint2* __restrict__ pairs, const int* __restrict__ bbase,
                               int* __restrict__ rowptr, float* __restrict__ dinv,
                               int* __restrict__ csr, uint2* __restrict__ bufA4,
                               int n_edges) {
    __shared__ int ndeg[256];
    __shared__ int nexcl[256];
    __shared__ int ncur[256];
    const int b   = blockIdx.x;
    const int tid = threadIdx.x;
    const int lo = bbase[b], hi = bbase[b + 1];
    const int n0 = b << BW_SHIFT;
    const int nn = min(256, NN - n0);

    ndeg[tid] = 0;
    __syncthreads();
    for (int i = lo + tid; i < hi; i += 256)
        atomicAdd(&ndeg[(int)pairs[i].x - n0], 1);
    __syncthreads();

    int v = ndeg[tid];
    nexcl[tid] = v;
    __syncthreads();
    for (int off = 1; off < 256; off <<= 1) {
        int t = (tid >= off) ? nexcl[tid - off] : 0;
        __syncthreads();
        nexcl[tid] += t;
        __syncthreads();
    }
    int excl = nexcl[tid] - v;
    float di = rsqrtf((float)(v + 1));

    if (tid < nn) {
        rowptr[n0 + tid] = lo + excl;
        dinv[n0 + tid] = di;
    }
    if (b == NB_BUCKET - 1 && tid == 0) rowptr[NN] = n_edges;
    ncur[tid] = lo + excl;
    __syncthreads();

    for (int i = lo + tid; i < hi; i += 256) {
        uint2 p = pairs[i];
        int pos = atomicAdd(&ncur[(int)p.x - n0], 1);
        csr[pos] = (int)p.y;
    }

    // scale h~ rows of this bucket by dinv (row = 128B contiguous per thread)
    if (tid < nn) {
        uint2* row = bufA4 + (size_t)(n0 + tid) * 16;
#pragma unroll 4
        for (int k = 0; k < 16; ++k) {
            uint2 w = row[k];
            __half2 a = *(__half2*)&w.x, c = *(__half2*)&w.y;
            float2 fa = __half22float2(a), fc = __half22float2(c);
            __half2 oa = __floats2half2_rn(fa.x * di, fa.y * di);
            __half2 oc = __floats2half2_rn(fc.x * di, fc.y * di);
            uint2 o; o.x = *(uint*)&oa; o.y = *(uint*)&oc;
            row[k] = o;
        }
    }
}

// ------------------------------------------------------------ MFMA GEMM ----
// (standalone, used for layer 2 where dinv is available)
template <int K, typename TIN>
__global__ void gemm_mfma_k(const TIN* __restrict__ X, const float* __restrict__ W,
                            const float* __restrict__ dinv, __half* __restrict__ Y,
                            int n_tiles) {
    __shared__ _Float16 Wl[K * 64];
    for (int i = threadIdx.x; i < K * 64; i += 256) Wl[i] = (_Float16)W[i];
    __syncthreads();

    const int lane = threadIdx.x & 63;
    const int wid  = threadIdx.x >> 6;
    const int col0 = lane & 15;
    const int kg   = lane >> 4;

    half8 bf[4][K / 32];
#pragma unroll
    for (int t = 0; t < 4; ++t)
#pragma unroll
        for (int s = 0; s < K / 32; ++s) {
            half8 b;
#pragma unroll
            for (int j = 0; j < 8; ++j)
                b[j] = Wl[(s * 32 + kg * 8 + j) * 64 + t * 16 + col0];
            bf[t][s] = b;
        }

    const int nwaves = gridDim.x * 4;
    for (int tile = blockIdx.x * 4 + wid; tile < n_tiles; tile += nwaves) {
        const int row0 = tile * 16;
        const int arow = row0 + col0;
        half8 af[K / 32];
#pragma unroll
        for (int s = 0; s < K / 32; ++s) {
            if constexpr (sizeof(TIN) == 4) {
                const float* p = (const float*)X + (size_t)arow * K + s * 32 + kg * 8;
                f32x4 v0 = *(const f32x4*)p;
                f32x4 v1 = *(const f32x4*)(p + 4);
                half8 a;
#pragma unroll
                for (int j = 0; j < 4; ++j) { a[j] = (_Float16)v0[j]; a[4 + j] = (_Float16)v1[j]; }
                af[s] = a;
            } else {
                const __half* p = (const __half*)X + (size_t)arow * K + s * 32 + kg * 8;
                af[s] = *(const half8*)p;
            }
        }
        f32x4 acc[4];
#pragma unroll
        for (int t = 0; t < 4; ++t) acc[t] = (f32x4){0.f, 0.f, 0.f, 0.f};
#pragma unroll
        for (int s = 0; s < K / 32; ++s)
#pragma unroll
            for (int t = 0; t < 4; ++t)
                acc[t] = __builtin_amdgcn_mfma_f32_16x16x32_f16(af[s], bf[t][s], acc[t], 0, 0, 0);

        float dv[4];
#pragma unroll
        for (int r = 0; r < 4; ++r) dv[r] = dinv[row0 + kg * 4 + r];
#pragma unroll
        for (int t = 0; t < 4; ++t)
#pragma unroll
            for (int r = 0; r < 4; ++r) {
                int row = row0 + kg * 4 + r;
                Y[(size_t)row * 64 + t * 16 + col0] = __float2half(acc[t][r] * dv[r]);
            }
    }
}

// --------------------------------------------------------------- gather -----
// HEAD=false: writes fp16 feature rows (layer 1).
// HEAD=true : fuses the final head — writes out[node] = relu(row) . W3 + b3.
template <bool HEAD>
__global__ void gather_k(const float2* __restrict__ H4, const float* __restrict__ dinv,
                         const int* __restrict__ rowptr, const int* __restrict__ csr,
                         const float* __restrict__ bias, uint2* __restrict__ out4,
                         const float* __restrict__ W3, const float* __restrict__ b3,
                         float* __restrict__ out1) {
    int node = (blockIdx.x * blockDim.x + threadIdx.x) >> 6;
    if (node >= NN) return;
    const int lane = threadIdx.x & 63;
    const int q  = lane >> 4;
    const int fl = lane & 15;

    const int p0 = rowptr[node], p1 = rowptr[node + 1];

    float4 acc = make_float4(0.f, 0.f, 0.f, 0.f);
    if (q == 0) {                  // self-loop row
        float2 v = H4[(size_t)node * 16 + fl];
        const __half2* h = (const __half2*)&v;
        float2 a = __half22float2(h[0]), b = __half22float2(h[1]);
        acc.x += a.x; acc.y += a.y; acc.z += b.x; acc.w += b.y;
    }

    for (int base = p0; base < p1; base += 64) {
        int pos = base + lane;
        int cidx = (pos < p1) ? csr[pos] : 0;
        int m = p1 - base; if (m > 64) m = 64;
        int jmax = (m + 3) >> 2;                    // wave-uniform trip count
#pragma unroll 4
        for (int j = 0; j < jmax; ++j) {
            int nb = (j << 2) + q;
            int s = __shfl(cidx, nb, 64);           // all 64 lanes execute
            if (nb < m) {
                float2 v = H4[(size_t)s * 16 + fl];
                const __half2* h = (const __half2*)&v;
                float2 a = __half22float2(h[0]), b = __half22float2(h[1]);
                acc.x += a.x; acc.y += a.y; acc.z += b.x; acc.w += b.y;
            }
        }
    }

    // butterfly: every lane ends with the full 4-quarter sum
    acc.x += __shfl_xor(acc.x, 16, 64); acc.y += __shfl_xor(acc.y, 16, 64);
    acc.z += __shfl_xor(acc.z, 16, 64); acc.w += __shfl_xor(acc.w, 16, 64);
    acc.x += __shfl_xor(acc.x, 32, 64); acc.y += __shfl_xor(acc.y, 32, 64);
    acc.z += __shfl_xor(acc.z, 32, 64); acc.w += __shfl_xor(acc.w, 32, 64);

    float di = dinv[node];
    float4 b = ((const float4*)bias)[fl];
    float vx = fmaxf(fmaf(acc.x, di, b.x), 0.f);
    float vy = fmaxf(fmaf(acc.y, di, b.y), 0.f);
    float vz = fmaxf(fmaf(acc.z, di, b.z), 0.f);
    float vw = fmaxf(fmaf(acc.w, di, b.w), 0.f);

    if constexpr (HEAD) {
        float4 w3 = ((const float4*)W3)[fl];
        float partial = vx * w3.x + vy * w3.y + vz * w3.z + vw * w3.w;
#pragma unroll
        for (int off = 1; off < 16; off <<= 1)
            partial += __shfl_xor(partial, off, 64);
        if (lane == 0) out1[node] = partial + b3[0];
    } else {
        if (q == 0) {
            __half2 lo = __floats2half2_rn(vx, vy), hi = __floats2half2_rn(vz, vw);
            uint2 o; o.x = *(const uint*)&lo; o.y = *(const uint*)&hi;
            out4[(size_t)node * 16 + fl] = o;
        }
    }
}

// ---------------------------------------------------------------------------
extern "C" void kernel_launch(void* const* d_in, const int* in_sizes, int n_in,
                              void* d_out, int out_size, void* d_ws, size_t ws_size,
                              hipStream_t stream) {
    const float* x   = (const float*)d_in[0];
    const int*   ei  = (const int*)d_in[1];
    const float* W1  = (const float*)d_in[2];
    const float* b1  = (const float*)d_in[3];
    const float* W2  = (const float*)d_in[4];
    const float* b2  = (const float*)d_in[5];
    const float* W3  = (const float*)d_in[6];
    const float* b3  = (const float*)d_in[7];
    float* out = (float*)d_out;

    const int E = in_sizes[1] / 2;
    const int* src = ei;
    const int* dst = ei + E;

    // workspace layout (4B units):
    // dinv[N] | rowptr[N+1] | bbase[512] | bcur[512] | csr[E] | bufA | bufB
    // pairs[E] (8B) overlays bufB (dead until gather1); bufA is written
    // concurrently by the fused GEMM1.
    float* dinv  = (float*)d_ws;
    int* rowptr  = (int*)(dinv + NN);
    int* bbase   = rowptr + NN + 1;
    int* bcur    = bbase + 512;
    int* csr     = bcur + 512;
    __half* bufA = (__half*)(csr + E);
    __half* bufB = bufA + (size_t)NN * EMB;
    uint2* pairs = (uint2*)bufB;               // overlay, CSR-build phase only

    const int B = 256;
    const int gNw = (NN * 64 + B - 1) / B;     // one wave per node
    const int nTiles = NN / 16;                // 6250 exact
    const int gGemm = (nTiles + 3) / 4;        // 1563
    const int nBin  = (E + 4095) / 4096;       // 391 chunks

    // ---- CSR build (binsort || GEMM1 overlapped) ----
    hipMemsetAsync(bbase, 0, 512 * sizeof(int), stream);
    bucket_cnt_k<<<512, B, 0, stream>>>(dst, bbase, E);
    bscan_k<<<1, 512, 0, stream>>>(bbase, bcur, E);
    binsort_gemm_k<<<nBin + gGemm, B, 0, stream>>>(src, dst, bcur, pairs, E, nBin,
                                                   x, W1, bufA, nTiles, gGemm);
    bucket_build_k<<<NB_BUCKET, B, 0, stream>>>(pairs, bbase, rowptr, dinv, csr,
                                                (uint2*)bufA, E);

    // ---- layer 1 aggregation ----
    gather_k<false><<<gNw, B, 0, stream>>>((const float2*)bufA, dinv, rowptr, csr, b1,
                                           (uint2*)bufB, nullptr, nullptr, nullptr);

    // ---- layer 2 + fused head ----
    gemm_mfma_k<EMB, __half><<<gGemm, B, 0, stream>>>(bufB, W2, dinv, bufA, nTiles);
    gather_k<true><<<gNw, B, 0, stream>>>((const float2*)bufA, dinv, rowptr, csr, b2,
                                          nullptr, W3, b3, out);
}

// Round 13
// 206.895 us; speedup vs baseline: 1.7559x; 1.0516x over previous
//
#include <hip/hip_runtime.h>
#include <hip/hip_bf16.h>
#include <hip/hip_fp16.h>

#define NN 100000     // nodes
#define FIN 128
#define EMB 64
#define BW_SHIFT 8                          // bucket = dst >> 8  (256 nodes)
#define NB_BUCKET ((NN + 255) / 256)        // 391

using half8 = __attribute__((ext_vector_type(8))) _Float16;
using f32x4 = __attribute__((ext_vector_type(4))) float;

#define BIN_LDS (4096 * 8 + 4 * NB_BUCKET * 4)     // 39024 B
#define GEMM_LDS (FIN * 64 * 2)                    // 16384 B
#define FUSED_LDS (BIN_LDS > GEMM_LDS ? BIN_LDS : GEMM_LDS)

// ----------------------------------------------------- bucket histogram -----
__global__ void bucket_cnt_k(const int* __restrict__ dst, int* __restrict__ bbase,
                             int n_edges) {
    __shared__ int bcnt[NB_BUCKET];
    for (int i = threadIdx.x; i < NB_BUCKET; i += 256) bcnt[i] = 0;
    __syncthreads();
    for (int e = blockIdx.x * 256 + threadIdx.x; e < n_edges; e += gridDim.x * 256)
        atomicAdd(&bcnt[dst[e] >> BW_SHIFT], 1);
    __syncthreads();
    for (int i = threadIdx.x; i < NB_BUCKET; i += 256) {
        int v = bcnt[i];
        if (v) atomicAdd(&bbase[i], v);
    }
}

// ----------------------------------------------------- bucket scan ----------
__global__ void bscan_k(int* __restrict__ bbase, int* __restrict__ bcur, int n_edges) {
    __shared__ int tmp[512];
    int tid = threadIdx.x;
    int v = (tid < NB_BUCKET) ? bbase[tid] : 0;
    tmp[tid] = v; __syncthreads();
    for (int off = 1; off < 512; off <<= 1) {
        int t = (tid >= off) ? tmp[tid - off] : 0; __syncthreads();
        tmp[tid] += t; __syncthreads();
    }
    int excl = tmp[tid] - v;
    if (tid < NB_BUCKET) { bbase[tid] = excl; bcur[tid] = excl; }
    if (tid == NB_BUCKET - 1) bbase[NB_BUCKET] = n_edges;
}

// ---------------------------------------- fused: binsort (A) || GEMM1 -------
__global__ void binsort_gemm_k(const int* __restrict__ src, const int* __restrict__ dst,
                               int* __restrict__ bcur, uint2* __restrict__ pairs,
                               int n_edges, int nBin,
                               const float* __restrict__ X, const float* __restrict__ W,
                               __half* __restrict__ Y, int n_tiles, int nGemm) {
    __shared__ __align__(16) char smraw[FUSED_LDS];
    const int tid = threadIdx.x;

    if (blockIdx.x < nBin) {
        // ---------------- binsort ----------------
        uint2* sorted = (uint2*)smraw;
        int* lcnt  = (int*)(smraw + 4096 * 8);
        int* loff  = lcnt + NB_BUCKET;
        int* lpos  = loff + NB_BUCKET;
        int* gbase = lpos + NB_BUCKET;
        const int lane = tid & 63;

        for (int chunk = blockIdx.x; chunk * 4096 < n_edges; chunk += nBin) {
            for (int i = tid; i < NB_BUCKET; i += 256) lcnt[i] = 0;
            __syncthreads();

            const int ebase = chunk * 4096;
            const int nval  = min(4096, n_edges - ebase);
            int d[16], s[16];
#pragma unroll
            for (int j = 0; j < 16; ++j) {
                int k = j * 256 + tid;
                if (k < nval) {
                    int e = ebase + k;
                    d[j] = dst[e]; s[j] = src[e];
                    atomicAdd(&lcnt[d[j] >> BW_SHIFT], 1);
                } else d[j] = -1;
            }
            __syncthreads();

            if (tid < 64) {                 // exclusive scan of lcnt
                int carry = 0;
                for (int seg = 0; seg < (NB_BUCKET + 63) / 64; ++seg) {
                    int i = seg * 64 + lane;
                    int v = (i < NB_BUCKET) ? lcnt[i] : 0;
                    int incl = v;
                    for (int off = 1; off < 64; off <<= 1) {
                        int idx = lane >= off ? lane - off : lane;
                        int t = __shfl(incl, idx, 64);
                        if (lane >= off) incl += t;
                    }
                    if (i < NB_BUCKET) loff[i] = incl - v + carry;
                    carry += __shfl(incl, 63, 64);
                }
            }
            __syncthreads();

            for (int i = tid; i < NB_BUCKET; i += 256) {
                lpos[i] = loff[i];
                int n = lcnt[i];
                gbase[i] = n ? atomicAdd(&bcur[i], n) : 0;
            }
            __syncthreads();

#pragma unroll
            for (int j = 0; j < 16; ++j) {
                if (d[j] >= 0) {
                    int b = d[j] >> BW_SHIFT;
                    int slot = atomicAdd(&lpos[b], 1);
                    sorted[slot] = make_uint2((unsigned)d[j], (unsigned)s[j]);
                }
            }
            __syncthreads();

            for (int i = tid; i < nval; i += 256) {
                uint2 p = sorted[i];
                int b = (int)(p.x >> BW_SHIFT);
                pairs[gbase[b] + (i - loff[b])] = p;
            }
            __syncthreads();
        }
    } else {
        // ---------------- GEMM1 (no dinv) ----------------
        _Float16* Wl = (_Float16*)smraw;
        for (int i = tid; i < FIN * 64; i += 256) Wl[i] = (_Float16)W[i];
        __syncthreads();

        const int lane = tid & 63;
        const int wid  = tid >> 6;
        const int col0 = lane & 15;
        const int kg   = lane >> 4;

        half8 bf[4][FIN / 32];
#pragma unroll
        for (int t = 0; t < 4; ++t)
#pragma unroll
            for (int s = 0; s < FIN / 32; ++s) {
                half8 b;
#pragma unroll
                for (int j = 0; j < 8; ++j)
                    b[j] = Wl[(s * 32 + kg * 8 + j) * 64 + t * 16 + col0];
                bf[t][s] = b;
            }

        const int gb = blockIdx.x - nBin;
        for (int tile = gb * 4 + wid; tile < n_tiles; tile += nGemm * 4) {
            const int arow = tile * 16 + col0;
            half8 af[FIN / 32];
#pragma unroll
            for (int s = 0; s < FIN / 32; ++s) {
                const float* p = X + (size_t)arow * FIN + s * 32 + kg * 8;
                f32x4 v0 = *(const f32x4*)p;
                f32x4 v1 = *(const f32x4*)(p + 4);
                half8 a;
#pragma unroll
                for (int j = 0; j < 4; ++j) { a[j] = (_Float16)v0[j]; a[4 + j] = (_Float16)v1[j]; }
                af[s] = a;
            }
            f32x4 acc[4];
#pragma unroll
            for (int t = 0; t < 4; ++t) acc[t] = (f32x4){0.f, 0.f, 0.f, 0.f};
#pragma unroll
            for (int s = 0; s < FIN / 32; ++s)
#pragma unroll
                for (int t = 0; t < 4; ++t)
                    acc[t] = __builtin_amdgcn_mfma_f32_16x16x32_f16(af[s], bf[t][s], acc[t], 0, 0, 0);
#pragma unroll
            for (int t = 0; t < 4; ++t)
#pragma unroll
                for (int r = 0; r < 4; ++r) {
                    int row = tile * 16 + kg * 4 + r;
                    Y[(size_t)row * 64 + t * 16 + col0] = __float2half(acc[t][r]);
                }
        }
    }
}

// -------------------------------------------- pass B: per-bucket CSR build --
__global__ void bucket_build_k(const uint2* __restrict__ pairs, const int* __restrict__ bbase,
                               int* __restrict__ rowptr, float* __restrict__ dinv,
                               int* __restrict__ csr, uint2* __restrict__ bufA4,
                               int n_edges) {
    __shared__ int ndeg[256];
    __shared__ int nexcl[256];
    __shared__ int ncur[256];
    const int b   = blockIdx.x;
    const int tid = threadIdx.x;
    const int lo = bbase[b], hi = bbase[b + 1];
    const int n0 = b << BW_SHIFT;
    const int nn = min(256, NN - n0);

    ndeg[tid] = 0;
    __syncthreads();
    for (int i = lo + tid; i < hi; i += 256)
        atomicAdd(&ndeg[(int)pairs[i].x - n0], 1);
    __syncthreads();

    int v = ndeg[tid];
    nexcl[tid] = v;
    __syncthreads();
    for (int off = 1; off < 256; off <<= 1) {
        int t = (tid >= off) ? nexcl[tid - off] : 0;
        __syncthreads();
        nexcl[tid] += t;
        __syncthreads();
    }
    int excl = nexcl[tid] - v;
    float di = rsqrtf((float)(v + 1));

    if (tid < nn) {
        rowptr[n0 + tid] = lo + excl;
        dinv[n0 + tid] = di;
    }
    if (b == NB_BUCKET - 1 && tid == 0) rowptr[NN] = n_edges;
    ncur[tid] = lo + excl;
    __syncthreads();

    for (int i = lo + tid; i < hi; i += 256) {
        uint2 p = pairs[i];
        int pos = atomicAdd(&ncur[(int)p.x - n0], 1);
        csr[pos] = (int)p.y;
    }

    // scale h~ rows of this bucket by dinv
    if (tid < nn) {
        uint2* row = bufA4 + (size_t)(n0 + tid) * 16;
#pragma unroll 4
        for (int k = 0; k < 16; ++k) {
            uint2 w = row[k];
            __half2 a = *(__half2*)&w.x, c = *(__half2*)&w.y;
            float2 fa = __half22float2(a), fc = __half22float2(c);
            __half2 oa = __floats2half2_rn(fa.x * di, fa.y * di);
            __half2 oc = __floats2half2_rn(fc.x * di, fc.y * di);
            uint2 o; o.x = *(uint*)&oa; o.y = *(uint*)&oc;
            row[k] = o;
        }
    }
}

// ------------------------------------------------------------ MFMA GEMM ----
template <int K, typename TIN>
__global__ void gemm_mfma_k(const TIN* __restrict__ X, const float* __restrict__ W,
                            const float* __restrict__ dinv, __half* __restrict__ Y,
                            int n_tiles) {
    __shared__ _Float16 Wl[K * 64];
    for (int i = threadIdx.x; i < K * 64; i += 256) Wl[i] = (_Float16)W[i];
    __syncthreads();

    const int lane = threadIdx.x & 63;
    const int wid  = threadIdx.x >> 6;
    const int col0 = lane & 15;
    const int kg   = lane >> 4;

    half8 bf[4][K / 32];
#pragma unroll
    for (int t = 0; t < 4; ++t)
#pragma unroll
        for (int s = 0; s < K / 32; ++s) {
            half8 b;
#pragma unroll
            for (int j = 0; j < 8; ++j)
                b[j] = Wl[(s * 32 + kg * 8 + j) * 64 + t * 16 + col0];
            bf[t][s] = b;
        }

    const int nwaves = gridDim.x * 4;
    for (int tile = blockIdx.x * 4 + wid; tile < n_tiles; tile += nwaves) {
        const int row0 = tile * 16;
        const int arow = row0 + col0;
        half8 af[K / 32];
#pragma unroll
        for (int s = 0; s < K / 32; ++s) {
            if constexpr (sizeof(TIN) == 4) {
                const float* p = (const float*)X + (size_t)arow * K + s * 32 + kg * 8;
                f32x4 v0 = *(const f32x4*)p;
                f32x4 v1 = *(const f32x4*)(p + 4);
                half8 a;
#pragma unroll
                for (int j = 0; j < 4; ++j) { a[j] = (_Float16)v0[j]; a[4 + j] = (_Float16)v1[j]; }
                af[s] = a;
            } else {
                const __half* p = (const __half*)X + (size_t)arow * K + s * 32 + kg * 8;
                af[s] = *(const half8*)p;
            }
        }
        f32x4 acc[4];
#pragma unroll
        for (int t = 0; t < 4; ++t) acc[t] = (f32x4){0.f, 0.f, 0.f, 0.f};
#pragma unroll
        for (int s = 0; s < K / 32; ++s)
#pragma unroll
            for (int t = 0; t < 4; ++t)
                acc[t] = __builtin_amdgcn_mfma_f32_16x16x32_f16(af[s], bf[t][s], acc[t], 0, 0, 0);

        float dv[4];
#pragma unroll
        for (int r = 0; r < 4; ++r) dv[r] = dinv[row0 + kg * 4 + r];
#pragma unroll
        for (int t = 0; t < 4; ++t)
#pragma unroll
            for (int r = 0; r < 4; ++r) {
                int row = row0 + kg * 4 + r;
                Y[(size_t)row * 64 + t * 16 + col0] = __float2half(acc[t][r] * dv[r]);
            }
    }
}

// --------------------------------------------------------------- gather -----
// One wave per node; 8 x 8-lane groups, each loads one FULL 128B fp16 row as
// uint4 (16B/lane) -> 8 independent row loads in flight per wave. csr indices
// read once per 64-neighbor chunk and distributed by shfl (wave-uniform trip
// count; only load/accumulate predicated). 3-level butterfly combine.
template <bool HEAD>
__global__ void gather_k(const uint4* __restrict__ H16, const float* __restrict__ dinv,
                         const int* __restrict__ rowptr, const int* __restrict__ csr,
                         const float* __restrict__ bias, uint4* __restrict__ out16,
                         const float* __restrict__ W3, const float* __restrict__ b3,
                         float* __restrict__ out1) {
    int node = (blockIdx.x * blockDim.x + threadIdx.x) >> 6;
    if (node >= NN) return;
    const int lane = threadIdx.x & 63;
    const int g  = lane >> 3;      // group 0..7 (row slot)
    const int fl = lane & 7;       // feature 8-pack (features 8fl..8fl+7)

    const int p0 = rowptr[node], p1 = rowptr[node + 1];

    float acc[8];
#pragma unroll
    for (int k = 0; k < 8; ++k) acc[k] = 0.f;

    if (g == 0) {                  // self-loop row
        uint4 v = H16[(size_t)node * 8 + fl];
        const __half2* h = (const __half2*)&v;
#pragma unroll
        for (int k = 0; k < 4; ++k) {
            float2 f = __half22float2(h[k]);
            acc[2 * k] += f.x; acc[2 * k + 1] += f.y;
        }
    }

    for (int base = p0; base < p1; base += 64) {
        int pos = base + lane;
        int cidx = (pos < p1) ? csr[pos] : 0;       // one coalesced read / chunk
        int m = p1 - base; if (m > 64) m = 64;
        int jmax = (m + 7) >> 3;                    // wave-uniform trip count
#pragma unroll 4
        for (int j = 0; j < jmax; ++j) {
            int nb = (j << 3) + g;                  // this group's neighbor slot
            int s = __shfl(cidx, nb, 64);           // all 64 lanes execute
            if (nb < m) {
                uint4 v = H16[(size_t)s * 8 + fl];
                const __half2* h = (const __half2*)&v;
#pragma unroll
                for (int k = 0; k < 4; ++k) {
                    float2 f = __half22float2(h[k]);
                    acc[2 * k] += f.x; acc[2 * k + 1] += f.y;
                }
            }
        }
    }

    // butterfly across the 8 groups: every lane ends with the full sum
#pragma unroll
    for (int off = 8; off < 64; off <<= 1)
#pragma unroll
        for (int k = 0; k < 8; ++k)
            acc[k] += __shfl_xor(acc[k], off, 64);

    float di = dinv[node];
    float4 b0 = ((const float4*)bias)[2 * fl];
    float4 b1v = ((const float4*)bias)[2 * fl + 1];
    float r[8];
    r[0] = fmaxf(fmaf(acc[0], di, b0.x), 0.f);
    r[1] = fmaxf(fmaf(acc[1], di, b0.y), 0.f);
    r[2] = fmaxf(fmaf(acc[2], di, b0.z), 0.f);
    r[3] = fmaxf(fmaf(acc[3], di, b0.w), 0.f);
    r[4] = fmaxf(fmaf(acc[4], di, b1v.x), 0.f);
    r[5] = fmaxf(fmaf(acc[5], di, b1v.y), 0.f);
    r[6] = fmaxf(fmaf(acc[6], di, b1v.z), 0.f);
    r[7] = fmaxf(fmaf(acc[7], di, b1v.w), 0.f);

    if constexpr (HEAD) {
        float4 w0 = ((const float4*)W3)[2 * fl];
        float4 w1 = ((const float4*)W3)[2 * fl + 1];
        float partial = r[0] * w0.x + r[1] * w0.y + r[2] * w0.z + r[3] * w0.w
                      + r[4] * w1.x + r[5] * w1.y + r[6] * w1.z + r[7] * w1.w;
#pragma unroll
        for (int off = 1; off < 8; off <<= 1)
            partial += __shfl_xor(partial, off, 64);
        if (lane == 0) out1[node] = partial + b3[0];
    } else {
        if (g == 0) {
            __half2 h[4];
#pragma unroll
            for (int k = 0; k < 4; ++k) h[k] = __floats2half2_rn(r[2 * k], r[2 * k + 1]);
            out16[(size_t)node * 8 + fl] = *(const uint4*)h;
        }
    }
}

// ---------------------------------------------------------------------------
extern "C" void kernel_launch(void* const* d_in, const int* in_sizes, int n_in,
                              void* d_out, int out_size, void* d_ws, size_t ws_size,
                              hipStream_t stream) {
    const float* x   = (const float*)d_in[0];
    const int*   ei  = (const int*)d_in[1];
    const float* W1  = (const float*)d_in[2];
    const float* b1  = (const float*)d_in[3];
    const float* W2  = (const float*)d_in[4];
    const float* b2  = (const float*)d_in[5];
    const float* W3  = (const float*)d_in[6];
    const float* b3  = (const float*)d_in[7];
    float* out = (float*)d_out;

    const int E = in_sizes[1] / 2;
    const int* src = ei;
    const int* dst = ei + E;

    // workspace layout (4B units):
    // dinv[N] | rowptr[N+1] | bbase[512] | bcur[512] | csr[E] | bufA | bufB
    float* dinv  = (float*)d_ws;
    int* rowptr  = (int*)(dinv + NN);
    int* bbase   = rowptr + NN + 1;
    int* bcur    = bbase + 512;
    int* csr     = bcur + 512;
    __half* bufA = (__half*)(csr + E);
    __half* bufB = bufA + (size_t)NN * EMB;
    uint2* pairs = (uint2*)bufB;               // overlay, CSR-build phase only

    const int B = 256;
    const int gNw = (NN * 64 + B - 1) / B;     // one wave per node
    const int nTiles = NN / 16;                // 6250 exact
    const int gGemm = (nTiles + 3) / 4;        // 1563
    const int nBin  = (E + 4095) / 4096;       // 391 chunks

    // ---- CSR build (binsort || GEMM1 overlapped) ----
    hipMemsetAsync(bbase, 0, 512 * sizeof(int), stream);
    bucket_cnt_k<<<512, B, 0, stream>>>(dst, bbase, E);
    bscan_k<<<1, 512, 0, stream>>>(bbase, bcur, E);
    binsort_gemm_k<<<nBin + gGemm, B, 0, stream>>>(src, dst, bcur, pairs, E, nBin,
                                                   x, W1, bufA, nTiles, gGemm);
    bucket_build_k<<<NB_BUCKET, B, 0, stream>>>(pairs, bbase, rowptr, dinv, csr,
                                                (uint2*)bufA, E);

    // ---- layer 1 aggregation ----
    gather_k<false><<<gNw, B, 0, stream>>>((const uint4*)bufA, dinv, rowptr, csr, b1,
                                           (uint4*)bufB, nullptr, nullptr, nullptr);

    // ---- layer 2 + fused head ----
    gemm_mfma_k<EMB, __half><<<gGemm, B, 0, stream>>>(bufB, W2, dinv, bufA, nTiles);
    gather_k<true><<<gNw, B, 0, stream>>>((const uint4*)bufA, dinv, rowptr, csr, b2,
                                          nullptr, W3, b3, out);
}